// Round 12
// baseline (90.920 us; speedup 1.0000x reference)
//
#include <hip/hip_runtime.h>
#include <math.h>

// Problem constants: FX=FY=48, CX=48, CY=36, H=72, W=96, sigma2=1
#define NPIX 6912
#define LOG2E 1.4426950408889634f

typedef __fp16 v8h  __attribute__((ext_vector_type(8)));
typedef float  v16f __attribute__((ext_vector_type(16)));

// Numerics (validated R5-R10, absmax 2.4e-7):
// A-side (rows, pixel m), [row][16] f16:
//   rowfeat: k0..15 = f1n features
//   rowgeo : k0..2=ph, k3..5=ph, k6..8=pl, k9=1, k10=1, k11=w_h, k12=w_l, k13..15=0
//            (p~ = log2e*p1 hi/lo split; w = -log2e*|p1|^2/2 hi/lo split)
// B-side (cols, pixel n), granule layout g=(c>>5)*64+h*32+(c&31), 8 halfs/granule:
//   colfeat: k0..15 = f2n features
//   colB1  : k0..2=th, k3..5=tl, k6..8=th, k9=cA_h, k10=cA_l, k11=1, k12=1, rest 0
//   colB2  : k0..2=dt, k3..5=0, k6..8=dt, k9=dc_h, k10=dc_l, rest 0
// MFMA(ageo,colB1) = p~.t (hi/lo cross) + cA + w = a1 (log2 exponent of e1)
// MFMA(ageo,colB2) = p~.dt + dc = delta (a2 - a1); e2 = e1 * 2^delta.
#define OFF_PART    0         // [2916] f32 pair partials
#define OFF_NPART   11664     // [2916] f32 norm partials
#define NLB 54                // logical grid is 54 x 54 blocks of 128x128
#define NPART_BLOCKS 2916

__device__ __forceinline__ float fast_exp2(float x) { return __builtin_amdgcn_exp2f(x); }

__device__ __forceinline__ float wave_reduce_64(float v) {
    #pragma unroll
    for (int o = 32; o > 0; o >>= 1) v += __shfl_down(v, o, 64);
    return v;
}

__device__ __forceinline__ float block_reduce_256(float v, float* smem4) {
    __syncthreads();
    v = wave_reduce_64(v);
    const int lane = threadIdx.x & 63;
    const int w = threadIdx.x >> 6;
    if (lane == 0) smem4[w] = v;
    __syncthreads();
    float r = 0.0f;
    if (threadIdx.x == 0) r = smem4[0] + smem4[1] + smem4[2] + smem4[3];
    return r;
}

__device__ __forceinline__ void split_hl(float x, __fp16& h, __fp16& l) {
    h = (__fp16)x;
    l = (__fp16)(x - (float)h);
}

// Fully fused pair kernel: grid (54,54), block = 256 threads (4 waves).
// Phase A: threads 0..127 preprocess the block's 128 row-pixels into LDS;
//          threads 128..255 preprocess its 128 col-pixels into LDS (granule
//          order). One __syncthreads. Redundant across blocks but tiny, and
//          removes the global workspace round-trip (cold-HBM first touches).
// Phase B: R10's proven loop — each wave owns one 32-row MFMA row-group,
//          sweeps 4 col-tiles of 32 (B from LDS, consecutive 16B/lane =
//          conflict-free ds_read_b128), dual accumulators, partial store.
// fea_norm_sum: bx==0 blocks contribute their 128 row-norms, by==0 blocks
// their 128 col-norms -> each pixel counted exactly once.
__global__ __launch_bounds__(256)
void pair_kernel(const float* __restrict__ f1, const float* __restrict__ f2,
                 const float* __restrict__ d1, const float* __restrict__ d2,
                 const float* __restrict__ pose, const float* __restrict__ pnz,
                 char* __restrict__ wsb) {
    __shared__ __align__(16) __fp16 srowfeat[128 * 16];   // 4 KB
    __shared__ __align__(16) __fp16 srowgeo [128 * 16];
    __shared__ __align__(16) __fp16 scolfeat[128 * 16];
    __shared__ __align__(16) __fp16 scolB1  [128 * 16];
    __shared__ __align__(16) __fp16 scolB2  [128 * 16];
    __shared__ float smem4[4];

    float* part  = (float*)(wsb + OFF_PART);
    float* npart = (float*)(wsb + OFF_NPART);

    const int t  = threadIdx.x;
    const int bx = blockIdx.x;
    const int by = blockIdx.y;

    // ---------------- phase A: block-local preprocessing ----------------
    const float inv48 = 1.0f / 48.0f;
    float nsum = 0.0f;

    if (t < 128) {
        // row pixel
        const int i = by * 128 + t;
        const int u = i % 96, v = i / 96;
        const float y1 = fmaf((float)u, inv48, -1.0f);
        const float y2 = fmaf((float)v, inv48, -0.75f);

        const float dep1 = d1[i];
        const float px = dep1, py = y1 * dep1, pz = y2 * dep1;
        const float n1 = px * px + py * py + pz * pz;
        const float wlog = -0.5f * LOG2E * n1;

        const float ptx = LOG2E * px, pty = LOG2E * py, ptz = LOG2E * pz;
        __fp16 phx, phy, phz, plx, ply, plz, wh, wl;
        split_hl(ptx, phx, plx);
        split_hl(pty, phy, ply);
        split_hl(ptz, phz, plz);
        split_hl(wlog, wh, wl);
        {
            __fp16 rg[16] = {phx, phy, phz,  phx, phy, phz,  plx, ply, plz,
                             (__fp16)1.0f, (__fp16)1.0f, wh, wl,
                             (__fp16)0, (__fp16)0, (__fp16)0};
            *(v8h*)(srowgeo + t * 16)     = *(v8h*)(rg);
            *(v8h*)(srowgeo + t * 16 + 8) = *(v8h*)(rg + 8);
        }

        float s1 = 0.0f;
        float v1[16];
        #pragma unroll
        for (int cc = 0; cc < 16; cc++) {
            v1[cc] = f1[cc * NPIX + i];
            s1 = fmaf(v1[cc], v1[cc], s1);
        }
        const float nrm1 = sqrtf(s1);
        const float r1 = 1.0f / (nrm1 + 1e-8f);
        {
            __fp16 rf[16];
            #pragma unroll
            for (int cc = 0; cc < 16; cc++) rf[cc] = (__fp16)(v1[cc] * r1);
            *(v8h*)(srowfeat + t * 16)     = *(v8h*)(rf);
            *(v8h*)(srowfeat + t * 16 + 8) = *(v8h*)(rf + 8);
        }
        if (bx == 0) nsum = nrm1;
    } else {
        // col pixel
        const int c = t - 128;
        const int n = bx * 128 + c;
        const int u = n % 96, v = n / 96;
        const float y1 = fmaf((float)u, inv48, -1.0f);
        const float y2 = fmaf((float)v, inv48, -0.75f);

        // pose rows 0..2 (uniform -> scalar)
        float P[12];
        #pragma unroll
        for (int k = 0; k < 12; k++) P[k] = pose[k];
        float Q[12];
        #pragma unroll
        for (int r = 0; r < 3; r++) {
            #pragma unroll
            for (int cq = 0; cq < 4; cq++) {
                float s = 0.0f;
                #pragma unroll
                for (int k = 0; k < 4; k++) s = fmaf(pose[r * 4 + k], pnz[k * 4 + cq], s);
                Q[r * 4 + cq] = s;
            }
        }

        const float dep2 = d2[n];
        const float a = dep2, b = y1 * dep2, g = y2 * dep2;
        const float t0 = P[0] * a + P[1] * b + P[2]  * g + P[3];
        const float t1 = P[4] * a + P[5] * b + P[6]  * g + P[7];
        const float t2 = P[8] * a + P[9] * b + P[10] * g + P[11];
        const float q0 = Q[0] * a + Q[1] * b + Q[2]  * g + Q[3];
        const float q1 = Q[4] * a + Q[5] * b + Q[6]  * g + Q[7];
        const float q2 = Q[8] * a + Q[9] * b + Q[10] * g + Q[11];
        const float nt = t0 * t0 + t1 * t1 + t2 * t2;
        const float nq = q0 * q0 + q1 * q1 + q2 * q2;
        const float cA = -0.5f * LOG2E * nt;
        const float dc = 0.5f * LOG2E * (nt - nq);

        __fp16 thx, thy, thz, tlx, tly, tlz, cAh, cAl, dch, dcl;
        split_hl(t0, thx, tlx);
        split_hl(t1, thy, tly);
        split_hl(t2, thz, tlz);
        split_hl(cA, cAh, cAl);
        split_hl(dc, dch, dcl);

        float s2 = 0.0f;
        float v2[16];
        #pragma unroll
        for (int cc = 0; cc < 16; cc++) {
            v2[cc] = f2[cc * NPIX + n];
            s2 = fmaf(v2[cc], v2[cc], s2);
        }
        const float nrm2 = sqrtf(s2);
        const float r2 = 1.0f / (nrm2 + 1e-8f);

        // granule base for this column: g(h) = (c>>5)*64 + h*32 + (c&31)
        const int g0 = (c >> 5) * 64 + (c & 31);
        {
            __fp16 cf[16];
            #pragma unroll
            for (int cc = 0; cc < 16; cc++) cf[cc] = (__fp16)(v2[cc] * r2);
            *(v8h*)(scolfeat + g0 * 8)        = *(v8h*)(cf);
            *(v8h*)(scolfeat + (g0 + 32) * 8) = *(v8h*)(cf + 8);
        }
        {
            __fp16 b1a[16] = {thx, thy, thz,  tlx, tly, tlz,  thx, thy, thz,
                              cAh, cAl, (__fp16)1.0f, (__fp16)1.0f,
                              (__fp16)0, (__fp16)0, (__fp16)0};
            *(v8h*)(scolB1 + g0 * 8)        = *(v8h*)(b1a);
            *(v8h*)(scolB1 + (g0 + 32) * 8) = *(v8h*)(b1a + 8);
        }
        const __fp16 dtx = (__fp16)(q0 - t0), dty = (__fp16)(q1 - t1), dtz = (__fp16)(q2 - t2);
        {
            __fp16 b2a[16] = {dtx, dty, dtz,  (__fp16)0, (__fp16)0, (__fp16)0,  dtx, dty, dtz,
                              dch, dcl, (__fp16)0, (__fp16)0,
                              (__fp16)0, (__fp16)0, (__fp16)0};
            *(v8h*)(scolB2 + g0 * 8)        = *(v8h*)(b2a);
            *(v8h*)(scolB2 + (g0 + 32) * 8) = *(v8h*)(b2a + 8);
        }
        if (by == 0) nsum = nrm2;
    }

    __syncthreads();

    // ---------------- phase B: MFMA pair sweep ----------------
    const int w   = t >> 6;
    const int L   = t & 63;
    const int c31 = L & 31;
    const int kh8 = (L >> 5) * 8;

    const int arowl = w * 32 + c31;
    const v8h afeat = *(const v8h*)(srowfeat + arowl * 16 + kh8);
    const v8h ageo  = *(const v8h*)(srowgeo  + arowl * 16 + kh8);

    float acc0 = 0.0f, acc1 = 0.0f;
    #pragma unroll
    for (int ct = 0; ct < 4; ct++) {
        const int off = (ct * 64 + L) * 8;
        const v8h bf = *(const v8h*)(scolfeat + off);
        const v8h b1 = *(const v8h*)(scolB1 + off);
        const v8h b2 = *(const v8h*)(scolB2 + off);

        v16f z = {};
        const v16f dotv = __builtin_amdgcn_mfma_f32_32x32x16_f16(afeat, bf, z, 0, 0, 0);
        const v16f a1v  = __builtin_amdgcn_mfma_f32_32x32x16_f16(ageo,  b1, z, 0, 0, 0);
        const v16f dlv  = __builtin_amdgcn_mfma_f32_32x32x16_f16(ageo,  b2, z, 0, 0, 0);

        #pragma unroll
        for (int i = 0; i < 8; i++) {
            const float e1a = fast_exp2(a1v[i]);
            const float e2a = fast_exp2(a1v[i] + dlv[i]);
            const float e1b = fast_exp2(a1v[i + 8]);
            const float e2b = fast_exp2(a1v[i + 8] + dlv[i + 8]);
            acc0 = fmaf(e1a - e2a, dotv[i], acc0);
            acc1 = fmaf(e1b - e2b, dotv[i + 8], acc1);
        }
    }

    // ---------------- reductions: one partial store each ----------------
    {
        const float v = wave_reduce_64(acc0 + acc1);
        if (L == 0) smem4[w] = v;
        __syncthreads();
        if (t == 0)
            part[by * NLB + bx] = smem4[0] + smem4[1] + smem4[2] + smem4[3];
    }
    {
        const float v = block_reduce_256(nsum, smem4);
        if (t == 0) npart[by * NLB + bx] = v;
    }
}

// Single-block finalize: reduce 2916 pair partials + 2916 norm partials,
// write all 3 outputs directly.
__global__ __launch_bounds__(256)
void finalize_kernel(const char* __restrict__ wsb, float* __restrict__ out) {
    __shared__ float smem4[4];
    const float* part  = (const float*)(wsb + OFF_PART);
    const float* npart = (const float*)(wsb + OFF_NPART);
    const int t = threadIdx.x;

    float s = 0.0f;
    for (int i = t; i < NPART_BLOCKS; i += 256) s += part[i];
    const float tot = block_reduce_256(s, smem4);

    float ns = 0.0f;
    for (int i = t; i < NPART_BLOCKS; i += 256) ns += npart[i];
    const float ntot = block_reduce_256(ns, smem4);

    if (t == 0) {
        const float vc = -tot * (1.0f / (float)NPIX);
        out[0] = vc;             // final_loss
        out[1] = vc;             // inner_neg
        out[2] = 100.0f * ntot;  // fea_norm_sum
    }
}

extern "C" void kernel_launch(void* const* d_in, const int* in_sizes, int n_in,
                              void* d_out, int out_size, void* d_ws, size_t ws_size,
                              hipStream_t stream) {
    const float* feature1 = (const float*)d_in[0];
    const float* feature2 = (const float*)d_in[1];
    const float* depth1   = (const float*)d_in[2];
    const float* depth2   = (const float*)d_in[3];
    const float* pose1_2  = (const float*)d_in[4];
    const float* posenz   = (const float*)d_in[5];
    float* out = (float*)d_out;
    char*  wsb = (char*)d_ws;

    dim3 grid(NLB, NLB);
    pair_kernel<<<grid, 256, 0, stream>>>(feature1, feature2, depth1, depth2,
                                          pose1_2, posenz, wsb);
    finalize_kernel<<<1, 256, 0, stream>>>(wsb, out);
}

// Round 13
// 85.852 us; speedup vs baseline: 1.0590x; 1.0590x over previous
//
#include <hip/hip_runtime.h>
#include <math.h>

// Problem constants: FX=FY=48, CX=48, CY=36, H=72, W=96, sigma2=1
#define NPIX 6912
#define LOG2E 1.4426950408889634f

typedef __fp16 v8h  __attribute__((ext_vector_type(8)));
typedef float  v16f __attribute__((ext_vector_type(16)));

// ws byte offsets (32B-aligned). All f16 arrays [N][16] (32 B per pixel).
// A-side (rows, pixel m):
//   rowfeat: k0..15 = f1n features (16)
//   rowgeo : k0..2=ph, k3..5=ph, k6..8=pl, k9=1, k10=1, k11=w_h, k12=w_l, k13..15=0
//            (p~ = log2e*p1 hi/lo split; w = -log2e*|p1|^2/2 hi/lo split)
// B-side (cols, pixel n):
//   colfeat: k0..15 = f2n features
//   colB1  : k0..2=th, k3..5=tl, k6..8=th, k9=cA_h, k10=cA_l, k11=1, k12=1, rest 0
//   colB2  : k0..2=qh, k3..5=ql, k6..8=qh, k9=cB_h, k10=cB_l, k11=1, k12=1, rest 0
//            (q-form, symmetric with colB1; cB = -log2e*|q|^2/2)
// MFMA(ageo,colB1) = p~.t + cA + w = a1 (log2 exponent of e1)
// MFMA(ageo,colB2) = p~.q + cB + w = a2 (log2 exponent of e2)
// (hi/lo cross products keep exponent error ~1e-4; pl*tl term dropped ~1e-8)
#define OFF_ROWFEAT 0
#define OFF_ROWGEO  221184
#define OFF_COLFEAT 442368
#define OFF_COLB1   663552
#define OFF_COLB2   884736
#define OFF_PART    1105920   // [1296] f32 pair-kernel block partials
#define OFF_NPART   1111104   // [108]  f32 preproc norm partials
#define NPART_BLOCKS 1296     // 24 x 54
#define NNORM_BLOCKS 108

__device__ __forceinline__ float fast_exp2(float x) { return __builtin_amdgcn_exp2f(x); }

__device__ __forceinline__ float wave_reduce_64(float v) {
    #pragma unroll
    for (int o = 32; o > 0; o >>= 1) v += __shfl_down(v, o, 64);
    return v;
}

__device__ __forceinline__ float block_reduce_256(float v, float* smem4) {
    __syncthreads();   // protect smem4 across consecutive reductions
    v = wave_reduce_64(v);
    const int lane = threadIdx.x & 63;
    const int w = threadIdx.x >> 6;
    if (lane == 0) smem4[w] = v;
    __syncthreads();
    float r = 0.0f;
    if (threadIdx.x == 0) r = smem4[0] + smem4[1] + smem4[2] + smem4[3];
    return r;
}

__device__ __forceinline__ void split_hl(float x, __fp16& h, __fp16& l) {
    h = (__fp16)x;
    l = (__fp16)(x - (float)h);
}

// 108 blocks x 64 threads (one wave per block); no atomics (partial store).
__global__ __launch_bounds__(64)
void preproc_kernel(const float* __restrict__ f1, const float* __restrict__ f2,
                    const float* __restrict__ d1, const float* __restrict__ d2,
                    const float* __restrict__ pose, const float* __restrict__ pnz,
                    char* __restrict__ wsb) {
    const int i = blockIdx.x * 64 + threadIdx.x;

    __fp16* rowfeat = (__fp16*)(wsb + OFF_ROWFEAT);
    __fp16* rowgeo  = (__fp16*)(wsb + OFF_ROWGEO);
    __fp16* colfeat = (__fp16*)(wsb + OFF_COLFEAT);
    __fp16* colB1   = (__fp16*)(wsb + OFF_COLB1);
    __fp16* colB2   = (__fp16*)(wsb + OFF_COLB2);
    float*  npart   = (float*)(wsb + OFF_NPART);

    // pose rows 0..2 (uniform -> scalar)
    float P[12];
    #pragma unroll
    for (int k = 0; k < 12; k++) P[k] = pose[k];
    float Q[12];
    #pragma unroll
    for (int r = 0; r < 3; r++) {
        #pragma unroll
        for (int c = 0; c < 4; c++) {
            float s = 0.0f;
            #pragma unroll
            for (int k = 0; k < 4; k++) s = fmaf(pose[r * 4 + k], pnz[k * 4 + c], s);
            Q[r * 4 + c] = s;
        }
    }

    const float inv48 = 1.0f / 48.0f;
    const int u = i % 96;
    const int v = i / 96;
    const float y1 = fmaf((float)u, inv48, -1.0f);
    const float y2 = fmaf((float)v, inv48, -0.75f);

    // ---- row side ----
    const float dep1 = d1[i];
    const float px = dep1, py = y1 * dep1, pz = y2 * dep1;
    const float n1 = px * px + py * py + pz * pz;
    const float wlog = -0.5f * LOG2E * n1;

    const float ptx = LOG2E * px, pty = LOG2E * py, ptz = LOG2E * pz;
    __fp16 phx, phy, phz, plx, ply, plz, wh, wl;
    split_hl(ptx, phx, plx);
    split_hl(pty, phy, ply);
    split_hl(ptz, phz, plz);
    split_hl(wlog, wh, wl);
    {
        __fp16 rg[16] = {phx, phy, phz,  phx, phy, phz,  plx, ply, plz,
                         (__fp16)1.0f, (__fp16)1.0f, wh, wl,
                         (__fp16)0, (__fp16)0, (__fp16)0};
        *(v8h*)(rowgeo + (size_t)i * 16)     = *(v8h*)(rg);
        *(v8h*)(rowgeo + (size_t)i * 16 + 8) = *(v8h*)(rg + 8);
    }

    // ---- col side ----
    const float dep2 = d2[i];
    const float a = dep2, b = y1 * dep2, g = y2 * dep2;
    const float t0 = P[0] * a + P[1] * b + P[2]  * g + P[3];
    const float t1 = P[4] * a + P[5] * b + P[6]  * g + P[7];
    const float t2 = P[8] * a + P[9] * b + P[10] * g + P[11];
    const float q0 = Q[0] * a + Q[1] * b + Q[2]  * g + Q[3];
    const float q1 = Q[4] * a + Q[5] * b + Q[6]  * g + Q[7];
    const float q2 = Q[8] * a + Q[9] * b + Q[10] * g + Q[11];
    const float nt = t0 * t0 + t1 * t1 + t2 * t2;
    const float nq = q0 * q0 + q1 * q1 + q2 * q2;
    const float cA = -0.5f * LOG2E * nt;
    const float cB = -0.5f * LOG2E * nq;

    __fp16 thx, thy, thz, tlx, tly, tlz, cAh, cAl;
    __fp16 qhx, qhy, qhz, qlx, qly, qlz, cBh, cBl;
    split_hl(t0, thx, tlx);
    split_hl(t1, thy, tly);
    split_hl(t2, thz, tlz);
    split_hl(cA, cAh, cAl);
    split_hl(q0, qhx, qlx);
    split_hl(q1, qhy, qly);
    split_hl(q2, qhz, qlz);
    split_hl(cB, cBh, cBl);
    {
        __fp16 b1a[16] = {thx, thy, thz,  tlx, tly, tlz,  thx, thy, thz,
                          cAh, cAl, (__fp16)1.0f, (__fp16)1.0f,
                          (__fp16)0, (__fp16)0, (__fp16)0};
        *(v8h*)(colB1 + (size_t)i * 16)     = *(v8h*)(b1a);
        *(v8h*)(colB1 + (size_t)i * 16 + 8) = *(v8h*)(b1a + 8);
    }
    {
        __fp16 b2a[16] = {qhx, qhy, qhz,  qlx, qly, qlz,  qhx, qhy, qhz,
                          cBh, cBl, (__fp16)1.0f, (__fp16)1.0f,
                          (__fp16)0, (__fp16)0, (__fp16)0};
        *(v8h*)(colB2 + (size_t)i * 16)     = *(v8h*)(b2a);
        *(v8h*)(colB2 + (size_t)i * 16 + 8) = *(v8h*)(b2a + 8);
    }

    // ---- features: normalize, f16 ----
    float s1 = 0.0f, s2 = 0.0f;
    float v1[16], v2[16];
    #pragma unroll
    for (int cc = 0; cc < 16; cc++) {
        v1[cc] = f1[cc * NPIX + i];
        v2[cc] = f2[cc * NPIX + i];
        s1 = fmaf(v1[cc], v1[cc], s1);
        s2 = fmaf(v2[cc], v2[cc], s2);
    }
    const float nrm1 = sqrtf(s1), nrm2 = sqrtf(s2);
    const float r1 = 1.0f / (nrm1 + 1e-8f), r2 = 1.0f / (nrm2 + 1e-8f);
    {
        __fp16 rf[16], cf[16];
        #pragma unroll
        for (int cc = 0; cc < 16; cc++) {
            rf[cc] = (__fp16)(v1[cc] * r1);
            cf[cc] = (__fp16)(v2[cc] * r2);
        }
        *(v8h*)(rowfeat + (size_t)i * 16)     = *(v8h*)(rf);
        *(v8h*)(rowfeat + (size_t)i * 16 + 8) = *(v8h*)(rf + 8);
        *(v8h*)(colfeat + (size_t)i * 16)     = *(v8h*)(cf);
        *(v8h*)(colfeat + (size_t)i * 16 + 8) = *(v8h*)(cf + 8);
    }

    float tot = wave_reduce_64(nrm1 + nrm2);
    if (threadIdx.x == 0) npart[blockIdx.x] = tot;
}

// Pair kernel: grid (24, 54), block = 4 waves. No LDS, no atomics.
// Each wave owns ONE 32-row MFMA row-group (block covers 128 rows) and sweeps
// 9 col-tiles of 32 columns (288 cols per block). 5184 waves = 5.1/SIMD.
// B-loads direct coalesced global (lane L -> col cbase+ct*32+(L&31), k-half
// L>>5: 64x16B = 1KB/instr), DEPTH-2 prefetch (3 rotating buffer triples) to
// cover cold-L2/HBM first-touch latency. Per slot: exp2(a1), exp2(a2) both
// independent MFMA consumers; dual accumulators. One partial store per block.
__global__ __launch_bounds__(256)
void pair_kernel(const char* __restrict__ wsb) {
    __shared__ float smem4[4];

    const __fp16* rowfeat = (const __fp16*)(wsb + OFF_ROWFEAT);
    const __fp16* rowgeo  = (const __fp16*)(wsb + OFF_ROWGEO);
    const __fp16* colfeat = (const __fp16*)(wsb + OFF_COLFEAT);
    const __fp16* colB1   = (const __fp16*)(wsb + OFF_COLB1);
    const __fp16* colB2   = (const __fp16*)(wsb + OFF_COLB2);
    float*        part    = (float*)(const_cast<char*>(wsb) + OFF_PART);

    const int t = threadIdx.x;
    const int w = t >> 6;
    const int L = t & 63;
    const int c31 = L & 31;
    const int kh8 = (L >> 5) * 8;

    // A fragments: loaded once, live across the column sweep
    const int arow = blockIdx.y * 128 + w * 32 + c31;
    const v8h afeat = *(const v8h*)(rowfeat + (size_t)arow * 16 + kh8);
    const v8h ageo  = *(const v8h*)(rowgeo  + (size_t)arow * 16 + kh8);

    const int cbase = blockIdx.x * 288;   // 9 tiles * 32 cols
    const size_t boff0 = (size_t)(cbase + c31) * 16 + kh8;

    float acc0 = 0.0f, acc1 = 0.0f;

    // depth-2 pipeline, 3 rotating buffers (fully unrolled -> static indices)
    v8h BF[3], B1[3], B2[3];
    #pragma unroll
    for (int s = 0; s < 2; s++) {
        const size_t o = boff0 + (size_t)s * 32 * 16;
        BF[s] = *(const v8h*)(colfeat + o);
        B1[s] = *(const v8h*)(colB1   + o);
        B2[s] = *(const v8h*)(colB2   + o);
    }

    #pragma unroll
    for (int ct = 0; ct < 9; ct++) {
        const int cur = ct % 3;
        if (ct < 7) {
            const int nxt = (ct + 2) % 3;
            const size_t o = boff0 + (size_t)(ct + 2) * 32 * 16;
            BF[nxt] = *(const v8h*)(colfeat + o);
            B1[nxt] = *(const v8h*)(colB1   + o);
            B2[nxt] = *(const v8h*)(colB2   + o);
        }

        v16f z = {};
        const v16f dotv = __builtin_amdgcn_mfma_f32_32x32x16_f16(afeat, BF[cur], z, 0, 0, 0);
        const v16f a1v  = __builtin_amdgcn_mfma_f32_32x32x16_f16(ageo,  B1[cur], z, 0, 0, 0);
        const v16f a2v  = __builtin_amdgcn_mfma_f32_32x32x16_f16(ageo,  B2[cur], z, 0, 0, 0);

        #pragma unroll
        for (int i = 0; i < 8; i++) {
            const float e1a = fast_exp2(a1v[i]);
            const float e2a = fast_exp2(a2v[i]);
            const float e1b = fast_exp2(a1v[i + 8]);
            const float e2b = fast_exp2(a2v[i + 8]);
            acc0 = fmaf(e1a - e2a, dotv[i], acc0);
            acc1 = fmaf(e1b - e2b, dotv[i + 8], acc1);
        }
    }

    // block reduction -> one plain store per block (no atomics)
    float v = wave_reduce_64(acc0 + acc1);
    if (L == 0) smem4[w] = v;
    __syncthreads();
    if (t == 0)
        part[blockIdx.y * 24 + blockIdx.x] = smem4[0] + smem4[1] + smem4[2] + smem4[3];
}

// Single-block finalize: reduce 1296 pair partials + 108 norm partials,
// write all 3 outputs directly.
__global__ __launch_bounds__(256)
void finalize_kernel(const char* __restrict__ wsb, float* __restrict__ out) {
    __shared__ float smem4[4];
    const float* part  = (const float*)(wsb + OFF_PART);
    const float* npart = (const float*)(wsb + OFF_NPART);
    const int t = threadIdx.x;

    float s = 0.0f;
    for (int i = t; i < NPART_BLOCKS; i += 256) s += part[i];
    const float tot = block_reduce_256(s, smem4);

    float ns = (t < NNORM_BLOCKS) ? npart[t] : 0.0f;
    const float ntot = block_reduce_256(ns, smem4);

    if (t == 0) {
        const float vc = -tot * (1.0f / (float)NPIX);
        out[0] = vc;             // final_loss
        out[1] = vc;             // inner_neg
        out[2] = 100.0f * ntot;  // fea_norm_sum
    }
}

extern "C" void kernel_launch(void* const* d_in, const int* in_sizes, int n_in,
                              void* d_out, int out_size, void* d_ws, size_t ws_size,
                              hipStream_t stream) {
    const float* feature1 = (const float*)d_in[0];
    const float* feature2 = (const float*)d_in[1];
    const float* depth1   = (const float*)d_in[2];
    const float* depth2   = (const float*)d_in[3];
    const float* pose1_2  = (const float*)d_in[4];
    const float* posenz   = (const float*)d_in[5];
    float* out = (float*)d_out;
    char*  wsb = (char*)d_ws;

    preproc_kernel<<<108, 64, 0, stream>>>(feature1, feature2, depth1, depth2,
                                           pose1_2, posenz, wsb);
    dim3 grid(24, 54);
    pair_kernel<<<grid, 256, 0, stream>>>(wsb);
    finalize_kernel<<<1, 256, 0, stream>>>(wsb, out);
}